// Round 7
// baseline (245.617 us; speedup 1.0000x reference)
//
#include <hip/hip_runtime.h>
#include <hip/hip_bf16.h>
#include <math.h>

#define M_TOT 8192
#define D_DIM 1024
#define E_NUM 8
#define P_DIM 1024
#define K_TOT (E_NUM * D_DIM)  // 8192

typedef __attribute__((ext_vector_type(8))) short short8;
typedef __attribute__((ext_vector_type(4))) float f32x4;
typedef __attribute__((ext_vector_type(8))) unsigned short u16x8;

// round-to-nearest-even f32 -> bf16 (finite inputs)
static __device__ __forceinline__ unsigned short f2bf(float f) {
  unsigned u = __builtin_bit_cast(unsigned, f);
  unsigned r = (u + 0x7fffu + ((u >> 16) & 1u)) >> 16;
  return (unsigned short)r;
}

// ---------------- gate: softmax(x @ gate_w + gate_b) -> [M, E] fp32 ----------------
__global__ __launch_bounds__(256) void gate_kernel(const float* __restrict__ x,
                                                   const float* __restrict__ gw,
                                                   const float* __restrict__ gb,
                                                   float* __restrict__ gate) {
  const int row  = blockIdx.x * 4 + (threadIdx.x >> 6);
  const int lane = threadIdx.x & 63;
  const float* xr = x + (size_t)row * D_DIM;
  float acc[E_NUM];
#pragma unroll
  for (int e = 0; e < E_NUM; ++e) acc[e] = 0.f;
#pragma unroll
  for (int it = 0; it < 16; ++it) {
    const int d = it * 64 + lane;
    const float xv = xr[d];
    const float4* g4 = reinterpret_cast<const float4*>(gw + (size_t)d * E_NUM);
    float4 a = g4[0], b = g4[1];
    acc[0] += xv * a.x; acc[1] += xv * a.y; acc[2] += xv * a.z; acc[3] += xv * a.w;
    acc[4] += xv * b.x; acc[5] += xv * b.y; acc[6] += xv * b.z; acc[7] += xv * b.w;
  }
#pragma unroll
  for (int off = 32; off >= 1; off >>= 1) {
#pragma unroll
    for (int e = 0; e < E_NUM; ++e) acc[e] += __shfl_xor(acc[e], off, 64);
  }
  if (lane == 0) {
    float v[E_NUM], mx = -1e30f;
#pragma unroll
    for (int e = 0; e < E_NUM; ++e) { v[e] = acc[e] + gb[e]; mx = fmaxf(mx, v[e]); }
    float s = 0.f;
#pragma unroll
    for (int e = 0; e < E_NUM; ++e) { v[e] = expf(v[e] - mx); s += v[e]; }
    const float inv = 1.f / s;
#pragma unroll
    for (int e = 0; e < E_NUM; ++e) gate[(size_t)row * E_NUM + e] = v[e] * inv;
  }
}

// ---- W [E][D][P] f32 -> wt [P][E*D] bf16, swizzle: chunk c -> c ^ ((p>>1)&3) within 32-short K-blocks ----
__global__ __launch_bounds__(256) void wtrans2_kernel(const float* __restrict__ w,
                                                      unsigned short* __restrict__ wt) {
  __shared__ float tile[64][65];
  const int e  = blockIdx.z;
  const int p0 = blockIdx.y * 64;
  const int d0 = blockIdx.x * 64;
  const int tx = threadIdx.x & 63;
  const int ty = threadIdx.x >> 6;
  const float* src = w + ((size_t)e * D_DIM + d0) * P_DIM + p0;
#pragma unroll
  for (int i = 0; i < 16; ++i) {
    const int dr = i * 4 + ty;
    tile[dr][tx] = src[(size_t)dr * P_DIM + tx];
  }
  __syncthreads();
#pragma unroll
  for (int i = 0; i < 16; ++i) {
    const int pr = i * 4 + ty;
    // logical k = e*1024 + d0 + tx; blk = k/32, chunk = (k%32)/8, j = k%8
    const int blk = e * 32 + (d0 >> 5) + (tx >> 5);
    const int c   = (tx >> 3) & 3;
    const int j   = tx & 7;
    const int cs  = c ^ ((pr >> 1) & 3);  // p0 is mult of 64 -> (p>>1)&3 == (pr>>1)&3
    wt[(size_t)(p0 + pr) * K_TOT + blk * 32 + cs * 8 + j] = f2bf(tile[tx][pr]);
  }
}

// ---- A'[m][e*1024+d] = bf16(gate[m,e]*x[m,d]), chunk c -> c ^ ((m>>1)&3) within 32-short blocks ----
__global__ __launch_bounds__(256) void aprep_kernel(const float* __restrict__ x,
                                                    const float* __restrict__ gate,
                                                    unsigned short* __restrict__ ap) {
  const int tid = threadIdx.x;
  const int m   = blockIdx.x * 2 + (tid >> 7);
  const int jd  = tid & 127;  // 8-elem chunk index within the 1024-wide d range
  const float4* xp = reinterpret_cast<const float4*>(x + (size_t)m * D_DIM + jd * 8);
  const float4 p = xp[0], q = xp[1];
  unsigned short* row = ap + (size_t)m * K_TOT;
  const int blk0 = jd >> 2;                       // block within expert slice (d/32)
  const int cs   = (jd & 3) ^ ((m >> 1) & 3);     // swizzled chunk
#pragma unroll
  for (int e = 0; e < E_NUM; ++e) {
    const float gs = gate[(size_t)m * E_NUM + e];
    u16x8 v;
    v[0] = f2bf(p.x * gs); v[1] = f2bf(p.y * gs);
    v[2] = f2bf(p.z * gs); v[3] = f2bf(p.w * gs);
    v[4] = f2bf(q.x * gs); v[5] = f2bf(q.y * gs);
    v[6] = f2bf(q.z * gs); v[7] = f2bf(q.w * gs);
    *reinterpret_cast<u16x8*>(&row[(size_t)(e * 32 + blk0) * 32 + cs * 8]) = v;
  }
}

// ---- split-K 256x256 GEMM, BK=32, quad-buffered LDS, 1 barrier + counted vmcnt(8) per tile ----
__global__ __launch_bounds__(512, 1) void gemm_q_kernel(
    const unsigned short* __restrict__ ap,
    const unsigned short* __restrict__ wt,
    const float* __restrict__ gate,
    const float* __restrict__ eb,
    float* __restrict__ out) {
  __shared__ __align__(16) unsigned short lA[4 * 8192];  // 4 bufs x 16 KB (256 rows x 32 shorts)
  __shared__ __align__(16) unsigned short lB[4 * 8192];  // 4 bufs x 16 KB
  __shared__ float lG[256 * 8];                          // 8 KB  -> 136 KB total

  const int tid  = threadIdx.x;
  const int lane = tid & 63;
  const int wid  = tid >> 6;
  const int wm   = wid >> 2;   // 0..1
  const int wn   = wid & 3;    // 0..3
  const int l15  = lane & 15;
  const int g8   = (lane >> 4);        // k-group 0..3 (x8 elems)

  // 256 blocks = 8 XCDs x (mtl4 x nt4 x kh2); XCD owns 4 m-tiles; kh pair on same XCD.
  const int bid = blockIdx.x;
  const int c   = bid & 7, j = bid >> 3;
  const int kh  = j & 1;
  const int nt  = (j >> 1) & 3;
  const int mt  = c * 4 + (j >> 3);
  const int m0  = mt * 256, n0 = nt * 256;
  const int kb  = kh * 128;   // K-block base (32-wide blocks; 128 per half)

  // gate tile [256][8]
  reinterpret_cast<float4*>(lG)[tid] =
      reinterpret_cast<const float4*>(gate + (size_t)m0 * E_NUM)[tid];

  // staging bases: thread u covers row = u>>2, stored-chunk = u&3 (linear in stored layout)
  const unsigned short* aB0 = ap + (size_t)(m0 + (tid >> 2)) * K_TOT + (tid & 3) * 8;
  const unsigned short* bB0 = wt + (size_t)(n0 + (tid >> 2)) * K_TOT + (tid & 3) * 8;

  auto stage = [&](int t) {
    const int w = kb + (t & 127);
    const int b = t & 3;
    const size_t wo = (size_t)w * 32;
    __builtin_amdgcn_global_load_lds(
        (const __attribute__((address_space(1))) void*)(aB0 + wo),
        (__attribute__((address_space(3))) void*)&lA[b * 8192 + tid * 8], 16, 0, 0);
    __builtin_amdgcn_global_load_lds(
        (const __attribute__((address_space(1))) void*)(aB0 + (size_t)128 * K_TOT + wo),
        (__attribute__((address_space(3))) void*)&lA[b * 8192 + (tid + 512) * 8], 16, 0, 0);
    __builtin_amdgcn_global_load_lds(
        (const __attribute__((address_space(1))) void*)(bB0 + wo),
        (__attribute__((address_space(3))) void*)&lB[b * 8192 + tid * 8], 16, 0, 0);
    __builtin_amdgcn_global_load_lds(
        (const __attribute__((address_space(1))) void*)(bB0 + (size_t)128 * K_TOT + wo),
        (__attribute__((address_space(3))) void*)&lB[b * 8192 + (tid + 512) * 8], 16, 0, 0);
  };

  f32x4 acc[8][4];
#pragma unroll
  for (int i = 0; i < 8; ++i)
#pragma unroll
    for (int jj = 0; jj < 4; ++jj)
#pragma unroll
      for (int k = 0; k < 4; ++k) acc[i][jj][k] = 0.f;

  // prologue: stage tiles 0,1,2 (12 loads); retire tile0's 4 -> vmcnt(8); publish
  stage(0); stage(1); stage(2);
  asm volatile("s_waitcnt vmcnt(8) lgkmcnt(0)" ::: "memory");
  __builtin_amdgcn_s_barrier();
  asm volatile("" ::: "memory");

#pragma unroll 1
  for (int t = 0; t < 128; ++t) {
    const int b = t & 3;
    const unsigned short* bufA = lA + b * 8192;
    const unsigned short* bufB = lB + b * 8192;

    // issue staging for t+3 first (its buffer's readers sealed at barrier(t-1))
    stage(t + 3);

    // fragment reads (conflict-free: chunk g8 ^ ((row>>1)&3) spreads all 8 bank-slots)
    short8 a[8], bfr[4];
#pragma unroll
    for (int mi = 0; mi < 8; ++mi) {
      const int r = wm * 128 + mi * 16 + l15;
      a[mi] = *reinterpret_cast<const short8*>(&bufA[r * 32 + ((g8 ^ ((r >> 1) & 3)) << 3)]);
    }
#pragma unroll
    for (int ni = 0; ni < 4; ++ni) {
      const int r = wn * 64 + ni * 16 + l15;
      bfr[ni] = *reinterpret_cast<const short8*>(&bufB[r * 32 + ((g8 ^ ((r >> 1) & 3)) << 3)]);
    }

    // 32 independent MFMAs (compiler interleaves with reads/stages freely)
    __builtin_amdgcn_s_setprio(1);
#pragma unroll
    for (int mi = 0; mi < 8; ++mi)
#pragma unroll
      for (int ni = 0; ni < 4; ++ni)
        acc[mi][ni] = __builtin_amdgcn_mfma_f32_16x16x32_bf16(a[mi], bfr[ni], acc[mi][ni], 0, 0, 0);
    __builtin_amdgcn_s_setprio(0);

    // end-of-tile: reads done (MFMA issue forces lgkm drain; belt anyway),
    // retire stages for tile t+1 (issued at t-2), publish to all waves.
    asm volatile("s_waitcnt lgkmcnt(0)" ::: "memory");
    asm volatile("s_waitcnt vmcnt(8)" ::: "memory");
    __builtin_amdgcn_s_barrier();
    asm volatile("" ::: "memory");
  }

  // ---- epilogue: atomic accumulate (+ gate-weighted bias on kh==0) ----
#pragma unroll
  for (int nf = 0; nf < 4; ++nf) {
    const int C = n0 + wn * 64 + nf * 16 + l15;
    float lb[E_NUM];
    if (kh == 0) {
#pragma unroll
      for (int e = 0; e < E_NUM; ++e) lb[e] = eb[(size_t)e * P_DIM + C];
    }
#pragma unroll
    for (int mf = 0; mf < 8; ++mf) {
#pragma unroll
      for (int reg = 0; reg < 4; ++reg) {
        const int rl = wm * 128 + mf * 16 + (lane >> 4) * 4 + reg;
        float v = acc[mf][nf][reg];
        if (kh == 0) {
          float bs = 0.f;
#pragma unroll
          for (int e = 0; e < E_NUM; ++e) bs += lG[rl * 8 + e] * lb[e];
          v += bs;
        }
        atomicAdd(&out[(size_t)(m0 + rl) * P_DIM + C], v);
      }
    }
  }
}

// ============================ FALLBACK PATH (round-2, passing) ============================

__global__ __launch_bounds__(256) void wtrans_kernel(const float* __restrict__ w,
                                                     unsigned short* __restrict__ wt) {
  __shared__ float tile[64][65];
  const int e  = blockIdx.z;
  const int p0 = blockIdx.y * 64;
  const int d0 = blockIdx.x * 64;
  const int tx = threadIdx.x & 63;
  const int ty = threadIdx.x >> 6;
  const float* src = w + ((size_t)e * D_DIM + d0) * P_DIM + p0;
#pragma unroll
  for (int i = 0; i < 16; ++i) {
    const int dr = i * 4 + ty;
    tile[dr][tx] = src[(size_t)dr * P_DIM + tx];
  }
  __syncthreads();
  unsigned short* dst = wt + ((size_t)e * P_DIM + p0) * D_DIM + d0;
#pragma unroll
  for (int i = 0; i < 16; ++i) {
    const int pr = i * 4 + ty;
    const int cc = tx ^ ((pr & 7) << 3);
    dst[(size_t)pr * D_DIM + cc] = f2bf(tile[tx][pr]);
  }
}

__global__ __launch_bounds__(256, 2) void moe_gemm_kernel(
    const float* __restrict__ x,
    const unsigned short* __restrict__ wt,
    const float* __restrict__ gate,
    const float* __restrict__ eb,
    float* __restrict__ out) {
  __shared__ unsigned short lA[128 * 64];
  __shared__ unsigned short lB[128 * 64];
  __shared__ float lG[128 * 8];
  __shared__ float lBias[E_NUM * 128];

  const int tid  = threadIdx.x;
  const int lane = tid & 63;
  const int wid  = tid >> 6;
  const int wr   = wid >> 1, wc = wid & 1;
  const int m0   = blockIdx.x * 128;
  const int n0   = blockIdx.y * 128;

  reinterpret_cast<float4*>(lG)[tid] =
      reinterpret_cast<const float4*>(gate + (size_t)m0 * E_NUM)[tid];
  {
    const int e = tid >> 5, cc = (tid & 31) * 4;
    *reinterpret_cast<float4*>(&lBias[e * 128 + cc]) =
        *reinterpret_cast<const float4*>(&eb[(size_t)e * P_DIM + n0 + cc]);
  }
  __syncthreads();

  const int rA   = tid >> 1;
  const int colA = (tid & 1) * 32;
  const float* xrow = x + (size_t)(m0 + rA) * D_DIM + colA;

  f32x4 acc[4][4];
#pragma unroll
  for (int i = 0; i < 4; ++i)
#pragma unroll
    for (int jj = 0; jj < 4; ++jj)
#pragma unroll
      for (int k = 0; k < 4; ++k) acc[i][jj][k] = 0.f;

  for (int e = 0; e < E_NUM; ++e) {
    const float gs = lG[rA * 8 + e];
    const unsigned short* wte = wt + ((size_t)e * P_DIM + n0) * D_DIM;
    for (int kt = 0; kt < 16; ++kt) {
      __syncthreads();
      const float4* apv = reinterpret_cast<const float4*>(xrow + kt * 64);
#pragma unroll
      for (int jj = 0; jj < 4; ++jj) {
        float4 p = apv[2 * jj], q = apv[2 * jj + 1];
        u16x8 v;
        v[0] = f2bf(p.x * gs); v[1] = f2bf(p.y * gs);
        v[2] = f2bf(p.z * gs); v[3] = f2bf(p.w * gs);
        v[4] = f2bf(q.x * gs); v[5] = f2bf(q.y * gs);
        v[6] = f2bf(q.z * gs); v[7] = f2bf(q.w * gs);
        const int idx = rA * 64 + ((colA + jj * 8) ^ ((rA & 7) << 3));
        *reinterpret_cast<u16x8*>(&lA[idx]) = v;
      }
#pragma unroll
      for (int i = 0; i < 4; ++i) {
        const int u  = tid + i * 256;
        const int rr = u >> 3;
        const int cc = u & 7;
        const unsigned short* src = wte + (size_t)rr * D_DIM + kt * 64 + cc * 8;
        __builtin_amdgcn_global_load_lds(
            (const __attribute__((address_space(1))) void*)src,
            (__attribute__((address_space(3))) void*)&lB[u * 8], 16, 0, 0);
      }
      __syncthreads();
#pragma unroll
      for (int kk = 0; kk < 2; ++kk) {
        const int e0 = kk * 32 + (lane >> 4) * 8;
        short8 a[4], b[4];
#pragma unroll
        for (int m = 0; m < 4; ++m) {
          const int r = wr * 64 + m * 16 + (lane & 15);
          a[m] = *reinterpret_cast<const short8*>(&lA[r * 64 + (e0 ^ ((r & 7) << 3))]);
        }
#pragma unroll
        for (int n = 0; n < 4; ++n) {
          const int r = wc * 64 + n * 16 + (lane & 15);
          b[n] = *reinterpret_cast<const short8*>(&lB[r * 64 + (e0 ^ ((r & 7) << 3))]);
        }
#pragma unroll
        for (int m = 0; m < 4; ++m)
#pragma unroll
          for (int n = 0; n < 4; ++n)
            acc[m][n] = __builtin_amdgcn_mfma_f32_16x16x32_bf16(a[m], b[n], acc[m][n], 0, 0, 0);
      }
    }
  }

#pragma unroll
  for (int m = 0; m < 4; ++m) {
#pragma unroll
    for (int n = 0; n < 4; ++n) {
      const int rbase = wr * 64 + m * 16 + ((lane >> 4) * 4);
      const int cl    = wc * 64 + n * 16 + (lane & 15);
#pragma unroll
      for (int reg = 0; reg < 4; ++reg) {
        const int r = rbase + reg;
        float bsum = 0.f;
#pragma unroll
        for (int e = 0; e < E_NUM; ++e) bsum += lG[r * 8 + e] * lBias[e * 128 + cl];
        out[(size_t)(m0 + r) * P_DIM + n0 + cl] = acc[m][n][reg] + bsum;
      }
    }
  }
}

// ============================ launch ============================

extern "C" void kernel_launch(void* const* d_in, const int* in_sizes, int n_in,
                              void* d_out, int out_size, void* d_ws, size_t ws_size,
                              hipStream_t stream) {
  const float* x  = (const float*)d_in[0];
  const float* gw = (const float*)d_in[1];
  const float* gb = (const float*)d_in[2];
  const float* ew = (const float*)d_in[3];
  const float* eb = (const float*)d_in[4];
  float* out = (float*)d_out;

  char* ws = (char*)d_ws;
  float* gate        = (float*)ws;                     // 256 KiB
  unsigned short* wt = (unsigned short*)(ws + 262144); // 16 MiB

  const size_t need_big = 262144ull + 16777216ull + 134217728ull;

  gate_kernel<<<M_TOT / 4, 256, 0, stream>>>(x, gw, gb, gate);

  if (ws_size >= need_big) {
    unsigned short* apb = (unsigned short*)(ws + 262144 + 16777216);  // 128 MiB
    hipMemsetAsync(d_out, 0, (size_t)out_size * sizeof(float), stream);
    wtrans2_kernel<<<dim3(D_DIM / 64, P_DIM / 64, E_NUM), 256, 0, stream>>>(ew, wt);
    aprep_kernel<<<M_TOT / 2, 256, 0, stream>>>(x, gate, apb);
    gemm_q_kernel<<<256, 512, 0, stream>>>(apb, wt, gate, eb, out);
  } else {
    wtrans_kernel<<<dim3(D_DIM / 64, P_DIM / 64, E_NUM), 256, 0, stream>>>(ew, wt);
    moe_gemm_kernel<<<dim3(M_TOT / 128, P_DIM / 128), 256, 0, stream>>>(x, wt, gate, eb, out);
  }
}

// Round 8
// 202.416 us; speedup vs baseline: 1.2134x; 1.2134x over previous
//
#include <hip/hip_runtime.h>
#include <hip/hip_bf16.h>
#include <math.h>

#define M_TOT 8192
#define D_DIM 1024
#define E_NUM 8
#define P_DIM 1024
#define K_TOT (E_NUM * D_DIM)  // 8192

typedef __attribute__((ext_vector_type(8))) short short8;
typedef __attribute__((ext_vector_type(4))) float f32x4;
typedef __attribute__((ext_vector_type(8))) unsigned short u16x8;

// round-to-nearest-even f32 -> bf16 (finite inputs)
static __device__ __forceinline__ unsigned short f2bf(float f) {
  unsigned u = __builtin_bit_cast(unsigned, f);
  unsigned r = (u + 0x7fffu + ((u >> 16) & 1u)) >> 16;
  return (unsigned short)r;
}

// ---------------- gate: softmax(x @ gate_w + gate_b) -> [M, E] fp32 ----------------
__global__ __launch_bounds__(256) void gate_kernel(const float* __restrict__ x,
                                                   const float* __restrict__ gw,
                                                   const float* __restrict__ gb,
                                                   float* __restrict__ gate) {
  const int row  = blockIdx.x * 4 + (threadIdx.x >> 6);
  const int lane = threadIdx.x & 63;
  const float* xr = x + (size_t)row * D_DIM;
  float acc[E_NUM];
#pragma unroll
  for (int e = 0; e < E_NUM; ++e) acc[e] = 0.f;
#pragma unroll
  for (int it = 0; it < 16; ++it) {
    const int d = it * 64 + lane;
    const float xv = xr[d];
    const float4* g4 = reinterpret_cast<const float4*>(gw + (size_t)d * E_NUM);
    float4 a = g4[0], b = g4[1];
    acc[0] += xv * a.x; acc[1] += xv * a.y; acc[2] += xv * a.z; acc[3] += xv * a.w;
    acc[4] += xv * b.x; acc[5] += xv * b.y; acc[6] += xv * b.z; acc[7] += xv * b.w;
  }
#pragma unroll
  for (int off = 32; off >= 1; off >>= 1) {
#pragma unroll
    for (int e = 0; e < E_NUM; ++e) acc[e] += __shfl_xor(acc[e], off, 64);
  }
  if (lane == 0) {
    float v[E_NUM], mx = -1e30f;
#pragma unroll
    for (int e = 0; e < E_NUM; ++e) { v[e] = acc[e] + gb[e]; mx = fmaxf(mx, v[e]); }
    float s = 0.f;
#pragma unroll
    for (int e = 0; e < E_NUM; ++e) { v[e] = expf(v[e] - mx); s += v[e]; }
    const float inv = 1.f / s;
#pragma unroll
    for (int e = 0; e < E_NUM; ++e) gate[(size_t)row * E_NUM + e] = v[e] * inv;
  }
}

// ---------------- W [E][D][P] f32 -> wt [P][E*D] bf16, swizzle baked per 64-short K-block ----------------
__global__ __launch_bounds__(256) void wtrans2_kernel(const float* __restrict__ w,
                                                      unsigned short* __restrict__ wt) {
  __shared__ float tile[64][65];
  const int e  = blockIdx.z;
  const int p0 = blockIdx.y * 64;
  const int d0 = blockIdx.x * 64;
  const int tx = threadIdx.x & 63;
  const int ty = threadIdx.x >> 6;
  const float* src = w + ((size_t)e * D_DIM + d0) * P_DIM + p0;
#pragma unroll
  for (int i = 0; i < 16; ++i) {
    const int dr = i * 4 + ty;
    tile[dr][tx] = src[(size_t)dr * P_DIM + tx];
  }
  __syncthreads();
#pragma unroll
  for (int i = 0; i < 16; ++i) {
    const int pr = i * 4 + ty;
    const int c = tx ^ ((pr & 7) << 3);  // involution, 16B-chunk granular
    wt[(size_t)(p0 + pr) * K_TOT + e * D_DIM + d0 + c] = f2bf(tile[tx][pr]);
  }
}

// ---------------- A'[m][e*1024+d] = bf16(gate[m,e]*x[m,d]), swizzle baked per 64-short K-block ----------------
__global__ __launch_bounds__(256) void aprep_kernel(const float* __restrict__ x,
                                                    const float* __restrict__ gate,
                                                    unsigned short* __restrict__ ap) {
  const int tid = threadIdx.x;
  const int m   = blockIdx.x * 2 + (tid >> 7);
  const int jd  = tid & 127;
  const float4* xp = reinterpret_cast<const float4*>(x + (size_t)m * D_DIM + jd * 8);
  const float4 p = xp[0], q = xp[1];
  unsigned short* row = ap + (size_t)m * K_TOT;
  const int cbase = (jd >> 3) * 8 + ((jd & 7) ^ (m & 7));
#pragma unroll
  for (int e = 0; e < E_NUM; ++e) {
    const float gs = gate[(size_t)m * E_NUM + e];
    u16x8 v;
    v[0] = f2bf(p.x * gs); v[1] = f2bf(p.y * gs);
    v[2] = f2bf(p.z * gs); v[3] = f2bf(p.w * gs);
    v[4] = f2bf(q.x * gs); v[5] = f2bf(q.y * gs);
    v[6] = f2bf(q.z * gs); v[7] = f2bf(q.w * gs);
    *reinterpret_cast<u16x8*>(&row[(size_t)(e * 128 + cbase) * 8]) = v;
  }
}

// ---- split-K=2 GEMM, round-3 structure: 128x128 tile, BK=64, 4 waves, 40KB LDS, 3-4 blocks/CU ----
__global__ __launch_bounds__(256, 3) void gemm_sk2_kernel(
    const unsigned short* __restrict__ ap,
    const unsigned short* __restrict__ wt,
    const float* __restrict__ gate,
    const float* __restrict__ eb,
    float* __restrict__ out) {
  __shared__ unsigned short lA[128 * 64];   // 16 KB
  __shared__ unsigned short lB[128 * 64];   // 16 KB
  __shared__ float lG[128 * 8];             // 4 KB
  __shared__ float lBias[E_NUM * 128];      // 4 KB  -> 40 KB total

  const int tid  = threadIdx.x;
  const int lane = tid & 63;
  const int wid  = tid >> 6;
  const int wr   = wid >> 1, wc = wid & 1;

  // 1024 blocks = 8 XCDs x (mtl8 x nt8 x kh2). All 16 blocks sharing an A'-panel
  // (same mt: 8 nt x 2 kh) sit on ONE XCD -> A panel L2-resident.
  const int bid = blockIdx.x;
  const int xcd = bid & 7, idx = bid >> 3;
  const int kh  = idx & 1;
  const int nt  = (idx >> 1) & 7;
  const int mt  = xcd * 8 + (idx >> 4);
  const int m0  = mt * 128, n0 = nt * 128;

  reinterpret_cast<float4*>(lG)[tid] =
      reinterpret_cast<const float4*>(gate + (size_t)m0 * E_NUM)[tid];
  {
    const int e = tid >> 5, c = (tid & 31) * 4;
    *reinterpret_cast<float4*>(&lBias[e * 128 + c]) =
        *reinterpret_cast<const float4*>(&eb[(size_t)e * P_DIM + n0 + c]);
  }

  f32x4 acc[4][4];
#pragma unroll
  for (int i = 0; i < 4; ++i)
#pragma unroll
    for (int j = 0; j < 4; ++j)
#pragma unroll
      for (int k = 0; k < 4; ++k) acc[i][j][k] = 0.f;

  const int r0 = tid >> 3;  // 0..31
  const int c8 = tid & 7;   // 16B chunk within 64-short block
  const unsigned short* pA = ap + (size_t)(m0 + r0) * K_TOT + (size_t)kh * 4096 + c8 * 8;
  const unsigned short* pB = wt + (size_t)(n0 + r0) * K_TOT + (size_t)kh * 4096 + c8 * 8;

  for (int kt = 0; kt < 64; ++kt) {
    __syncthreads();  // previous tile's LDS reads complete
#pragma unroll
    for (int i = 0; i < 4; ++i) {
      __builtin_amdgcn_global_load_lds(
          (const __attribute__((address_space(1))) void*)(pA + (size_t)i * 32 * K_TOT),
          (__attribute__((address_space(3))) void*)&lA[(tid + i * 256) * 8], 16, 0, 0);
    }
#pragma unroll
    for (int i = 0; i < 4; ++i) {
      __builtin_amdgcn_global_load_lds(
          (const __attribute__((address_space(1))) void*)(pB + (size_t)i * 32 * K_TOT),
          (__attribute__((address_space(3))) void*)&lB[(tid + i * 256) * 8], 16, 0, 0);
    }
    __syncthreads();  // compiler drains vmcnt before barrier
#pragma unroll
    for (int kk = 0; kk < 2; ++kk) {
      const int e0 = kk * 32 + (lane >> 4) * 8;
      short8 a[4], b[4];
#pragma unroll
      for (int m = 0; m < 4; ++m) {
        const int r = wr * 64 + m * 16 + (lane & 15);
        a[m] = *reinterpret_cast<const short8*>(&lA[r * 64 + (e0 ^ ((r & 7) << 3))]);
      }
#pragma unroll
      for (int n = 0; n < 4; ++n) {
        const int r = wc * 64 + n * 16 + (lane & 15);
        b[n] = *reinterpret_cast<const short8*>(&lB[r * 64 + (e0 ^ ((r & 7) << 3))]);
      }
#pragma unroll
      for (int m = 0; m < 4; ++m)
#pragma unroll
        for (int n = 0; n < 4; ++n)
          acc[m][n] = __builtin_amdgcn_mfma_f32_16x16x32_bf16(a[m], b[n], acc[m][n], 0, 0, 0);
    }
    pA += 64;
    pB += 64;
  }

  // ---- epilogue: atomic accumulate; kh==0 adds gate-weighted bias ----
#pragma unroll
  for (int m = 0; m < 4; ++m) {
#pragma unroll
    for (int n = 0; n < 4; ++n) {
      const int rbase = wr * 64 + m * 16 + ((lane >> 4) * 4);
      const int cl    = wc * 64 + n * 16 + (lane & 15);
#pragma unroll
      for (int reg = 0; reg < 4; ++reg) {
        const int r = rbase + reg;
        float v = acc[m][n][reg];
        if (kh == 0) {
          float bsum = 0.f;
#pragma unroll
          for (int e = 0; e < E_NUM; ++e) bsum += lG[r * 8 + e] * lBias[e * 128 + cl];
          v += bsum;
        }
        atomicAdd(&out[(size_t)(m0 + r) * P_DIM + n0 + cl], v);
      }
    }
  }
}

// ============================ FALLBACK PATH (round-2, passing) ============================

__global__ __launch_bounds__(256) void wtrans_kernel(const float* __restrict__ w,
                                                     unsigned short* __restrict__ wt) {
  __shared__ float tile[64][65];
  const int e  = blockIdx.z;
  const int p0 = blockIdx.y * 64;
  const int d0 = blockIdx.x * 64;
  const int tx = threadIdx.x & 63;
  const int ty = threadIdx.x >> 6;
  const float* src = w + ((size_t)e * D_DIM + d0) * P_DIM + p0;
#pragma unroll
  for (int i = 0; i < 16; ++i) {
    const int dr = i * 4 + ty;
    tile[dr][tx] = src[(size_t)dr * P_DIM + tx];
  }
  __syncthreads();
  unsigned short* dst = wt + ((size_t)e * P_DIM + p0) * D_DIM + d0;
#pragma unroll
  for (int i = 0; i < 16; ++i) {
    const int pr = i * 4 + ty;
    const int cc = tx ^ ((pr & 7) << 3);
    dst[(size_t)pr * D_DIM + cc] = f2bf(tile[tx][pr]);
  }
}

__global__ __launch_bounds__(256, 2) void moe_gemm_kernel(
    const float* __restrict__ x,
    const unsigned short* __restrict__ wt,
    const float* __restrict__ gate,
    const float* __restrict__ eb,
    float* __restrict__ out) {
  __shared__ unsigned short lA[128 * 64];
  __shared__ unsigned short lB[128 * 64];
  __shared__ float lG[128 * 8];
  __shared__ float lBias[E_NUM * 128];

  const int tid  = threadIdx.x;
  const int lane = tid & 63;
  const int wid  = tid >> 6;
  const int wr   = wid >> 1, wc = wid & 1;
  const int m0   = blockIdx.x * 128;
  const int n0   = blockIdx.y * 128;

  reinterpret_cast<float4*>(lG)[tid] =
      reinterpret_cast<const float4*>(gate + (size_t)m0 * E_NUM)[tid];
  {
    const int e = tid >> 5, cc = (tid & 31) * 4;
    *reinterpret_cast<float4*>(&lBias[e * 128 + cc]) =
        *reinterpret_cast<const float4*>(&eb[(size_t)e * P_DIM + n0 + cc]);
  }
  __syncthreads();

  const int rA   = tid >> 1;
  const int colA = (tid & 1) * 32;
  const float* xrow = x + (size_t)(m0 + rA) * D_DIM + colA;

  f32x4 acc[4][4];
#pragma unroll
  for (int i = 0; i < 4; ++i)
#pragma unroll
    for (int jj = 0; jj < 4; ++jj)
#pragma unroll
      for (int k = 0; k < 4; ++k) acc[i][jj][k] = 0.f;

  for (int e = 0; e < E_NUM; ++e) {
    const float gs = lG[rA * 8 + e];
    const unsigned short* wte = wt + ((size_t)e * P_DIM + n0) * D_DIM;
    for (int kt = 0; kt < 16; ++kt) {
      __syncthreads();
      const float4* apv = reinterpret_cast<const float4*>(xrow + kt * 64);
#pragma unroll
      for (int jj = 0; jj < 4; ++jj) {
        float4 p = apv[2 * jj], q = apv[2 * jj + 1];
        u16x8 v;
        v[0] = f2bf(p.x * gs); v[1] = f2bf(p.y * gs);
        v[2] = f2bf(p.z * gs); v[3] = f2bf(p.w * gs);
        v[4] = f2bf(q.x * gs); v[5] = f2bf(q.y * gs);
        v[6] = f2bf(q.z * gs); v[7] = f2bf(q.w * gs);
        const int idx = rA * 64 + ((colA + jj * 8) ^ ((rA & 7) << 3));
        *reinterpret_cast<u16x8*>(&lA[idx]) = v;
      }
#pragma unroll
      for (int i = 0; i < 4; ++i) {
        const int u  = tid + i * 256;
        const int rr = u >> 3;
        const int cc = u & 7;
        const unsigned short* src = wte + (size_t)rr * D_DIM + kt * 64 + cc * 8;
        __builtin_amdgcn_global_load_lds(
            (const __attribute__((address_space(1))) void*)src,
            (__attribute__((address_space(3))) void*)&lB[u * 8], 16, 0, 0);
      }
      __syncthreads();
#pragma unroll
      for (int kk = 0; kk < 2; ++kk) {
        const int e0 = kk * 32 + (lane >> 4) * 8;
        short8 a[4], b[4];
#pragma unroll
        for (int m = 0; m < 4; ++m) {
          const int r = wr * 64 + m * 16 + (lane & 15);
          a[m] = *reinterpret_cast<const short8*>(&lA[r * 64 + (e0 ^ ((r & 7) << 3))]);
        }
#pragma unroll
        for (int n = 0; n < 4; ++n) {
          const int r = wc * 64 + n * 16 + (lane & 15);
          b[n] = *reinterpret_cast<const short8*>(&lB[r * 64 + (e0 ^ ((r & 7) << 3))]);
        }
#pragma unroll
        for (int m = 0; m < 4; ++m)
#pragma unroll
          for (int n = 0; n < 4; ++n)
            acc[m][n] = __builtin_amdgcn_mfma_f32_16x16x32_bf16(a[m], b[n], acc[m][n], 0, 0, 0);
      }
    }
  }

#pragma unroll
  for (int m = 0; m < 4; ++m) {
#pragma unroll
    for (int n = 0; n < 4; ++n) {
      const int rbase = wr * 64 + m * 16 + ((lane >> 4) * 4);
      const int cl    = wc * 64 + n * 16 + (lane & 15);
#pragma unroll
      for (int reg = 0; reg < 4; ++reg) {
        const int r = rbase + reg;
        float bsum = 0.f;
#pragma unroll
        for (int e = 0; e < E_NUM; ++e) bsum += lG[r * 8 + e] * lBias[e * 128 + cl];
        out[(size_t)(m0 + r) * P_DIM + n0 + cl] = acc[m][n][reg] + bsum;
      }
    }
  }
}

// ============================ launch ============================

extern "C" void kernel_launch(void* const* d_in, const int* in_sizes, int n_in,
                              void* d_out, int out_size, void* d_ws, size_t ws_size,
                              hipStream_t stream) {
  const float* x  = (const float*)d_in[0];
  const float* gw = (const float*)d_in[1];
  const float* gb = (const float*)d_in[2];
  const float* ew = (const float*)d_in[3];
  const float* eb = (const float*)d_in[4];
  float* out = (float*)d_out;

  char* ws = (char*)d_ws;
  float* gate        = (float*)ws;                     // 256 KiB
  unsigned short* wt = (unsigned short*)(ws + 262144); // 16 MiB

  const size_t need_big = 262144ull + 16777216ull + 134217728ull;

  gate_kernel<<<M_TOT / 4, 256, 0, stream>>>(x, gw, gb, gate);

  if (ws_size >= need_big) {
    unsigned short* apb = (unsigned short*)(ws + 262144 + 16777216);  // 128 MiB
    hipMemsetAsync(d_out, 0, (size_t)out_size * sizeof(float), stream);
    wtrans2_kernel<<<dim3(D_DIM / 64, P_DIM / 64, E_NUM), 256, 0, stream>>>(ew, wt);
    aprep_kernel<<<M_TOT / 2, 256, 0, stream>>>(x, gate, apb);
    gemm_sk2_kernel<<<1024, 256, 0, stream>>>(apb, wt, gate, eb, out);
  } else {
    wtrans_kernel<<<dim3(D_DIM / 64, P_DIM / 64, E_NUM), 256, 0, stream>>>(ew, wt);
    moe_gemm_kernel<<<dim3(M_TOT / 128, P_DIM / 128), 256, 0, stream>>>(x, wt, gate, eb, out);
  }
}